// Round 6
// baseline (548.687 us; speedup 1.0000x reference)
//
#include <hip/hip_runtime.h>
#include <cstddef>

// DynamicNetwork via split-bf16 MFMA (hi/lo, 3 MFMA per product).
// R6: LDS-free fragment loads kept; TLP restored via 4-way K-split:
// 4 waves/block share one 64x64 tile, each covering k16 steps {w, w+4, ...},
// partials combined through a padded LDS buffer (2 rounds, conflict-free).

typedef short short8 __attribute__((ext_vector_type(8)));
typedef float floatx16 __attribute__((ext_vector_type(16)));

#define EMB_BLOCKS 832
// padded strides (elements)
#define SN0 224   // node0 k-stride (208 used)
#define SN1 448   // node1 k-stride (416 used)
#define SH  416   // hidden/node k-stride (400 used)

__device__ __forceinline__ unsigned short f2bf(float f) {
    unsigned int u = __float_as_uint(f);
    u += 0x7fffu + ((u >> 16) & 1u);
    return (unsigned short)(u >> 16);
}
__device__ __forceinline__ float bf2f(unsigned short h) {
    return __uint_as_float((unsigned int)h << 16);
}
__device__ __forceinline__ void split2(float v, unsigned short& h, unsigned short& l) {
    h = f2bf(v);
    l = f2bf(v - bf2f(h));
}

// ---------------- prep1: column sums + alpha scalars ----------------
__global__ __launch_bounds__(256) void prep1_kernel(
    const float* __restrict__ Pd, const float* __restrict__ Ps, const float* __restrict__ Pb,
    const float* __restrict__ a0, const float* __restrict__ a1,
    const float* __restrict__ a2, const float* __restrict__ a3,
    float* __restrict__ scal,
    float* __restrict__ csd, float* __restrict__ css, float* __restrict__ csb)
{
    int gid = blockIdx.x * 256 + threadIdx.x;
    if (gid < 400) {
        float s = 0.f;
        for (int k = 0; k < 208; ++k) s += Pd[k*400 + gid];
        csd[gid] = s;
    } else if (gid < 800) {
        int j = gid - 400; float s = 0.f;
        for (int k = 0; k < 416; ++k) s += Ps[k*400 + j];
        css[j] = s;
    } else if (gid < 1200) {
        int j = gid - 800; float s = 0.f;
        for (int k = 0; k < 400; ++k) s += Pb[k*400 + j];
        csb[j] = s;
    } else if (gid < 1204) {
        int i = gid - 1200;
        const float* a = (i==0) ? a0 : (i==1) ? a1 : (i==2) ? a2 : a3;
        int np = 2 + i;
        float sum1 = 0.f, sum2 = 0.f, sumc = 0.f;
        for (int j = 0; j < np; ++j) { sum1 += a[j]; sum2 += a[np+j]; }
        for (int j = 0; j < 4; ++j) sumc += a[2*np+j];
        int i1 = (i==0) ? 0 : 1;
        int i2 = i + 1;
        int kk = i;
        float s1 = a[i1],      c1 = sum1 - s1;
        float s2 = a[np+i2],   c2 = sum2 - s2;
        float sk = a[2*np+kk], ck = sumc - sk;
        float* sl = scal + i*8;
        if (i == 0) { sl[0]=s1; sl[1]=c1; sl[2]=s2; sl[3]=c2; }
        else        { sl[0]=s2; sl[1]=c2; sl[2]=s1; sl[3]=c1; }
        sl[4] = sk; sl[5] = ck;
    }
}

// ---------------- prep2: transpose + scale + split weights -> [448][Kw] bf16 hi|lo planes
__global__ __launch_bounds__(256) void prep2_kernel(
    const float* __restrict__ Pd, const float* __restrict__ Ps,
    const float* __restrict__ Pb, const float* __restrict__ Wc,
    const float* __restrict__ scal,
    unsigned short* __restrict__ w0, unsigned short* __restrict__ w1,
    unsigned short* __restrict__ w2, unsigned short* __restrict__ w3,
    unsigned short* __restrict__ v0, unsigned short* __restrict__ v1,
    unsigned short* __restrict__ v2, unsigned short* __restrict__ v3)
{
    int z = blockIdx.z;
    int Kp, KA, Kw; const float *sA, *sB; float sc1, sc2; unsigned short* dst;
    if (z < 4) {
        Kp = (z==0) ? 624 : 816; KA = (z==0) ? 208 : 400; Kw = (z==0) ? 640 : 832;
        sA = (z==0) ? Pd : Pb; sB = Ps;
        sc1 = scal[z*8+0]; sc2 = scal[z*8+2];
        dst = (z==0) ? w0 : (z==1) ? w1 : (z==2) ? w2 : w3;
    } else {
        int i = z - 4;
        Kp = 400; KA = 400; Kw = 416;
        sA = Wc + (size_t)i*5*160000; sB = nullptr;
        sc1 = scal[i*8+4]; sc2 = 0.f;
        dst = (i==0) ? v0 : (i==1) ? v1 : (i==2) ? v2 : v3;
    }
    int ktiles = (Kp + 63) >> 6;
    if ((int)blockIdx.y >= ktiles) return;
    int k0 = blockIdx.y * 64, n0 = blockIdx.x * 64;
    __shared__ float T[64][65];
    int t = threadIdx.x;
    {
        int kr = t >> 2, c0 = (t & 3) * 16;
        int gk = k0 + kr;
        bool kok = gk < Kp;
        const float* src; int srow; float sc;
        if (gk < KA) { src = sA; srow = gk; sc = sc1; }
        else         { src = sB; srow = gk - KA; sc = sc2; }
        for (int j = 0; j < 16; j += 4) {
            int n = n0 + c0 + j;
            float4 v = make_float4(0.f,0.f,0.f,0.f);
            if (kok && n < 400) v = *(const float4*)&src[(size_t)srow*400 + n];
            T[kr][c0+j+0] = v.x * sc;
            T[kr][c0+j+1] = v.y * sc;
            T[kr][c0+j+2] = v.z * sc;
            T[kr][c0+j+3] = v.w * sc;
        }
    }
    __syncthreads();
    {
        int nr = t >> 2, kc0 = (t & 3) * 16;
        int gn = n0 + nr;
        int gk0 = k0 + kc0;
        if (gk0 >= Kp) return;
        unsigned short hb[16], lb[16];
        for (int j = 0; j < 16; ++j) {
            float v = (gn < 400) ? T[kc0+j][nr] : 0.f;
            split2(v, hb[j], lb[j]);
        }
        unsigned short* dh = dst + (size_t)gn*Kw + gk0;
        unsigned short* dl = dst + (size_t)448*Kw + (size_t)gn*Kw + gk0;
        *(uint4*)&dh[0] = *(uint4*)&hb[0]; *(uint4*)&dh[8] = *(uint4*)&hb[8];
        *(uint4*)&dl[0] = *(uint4*)&lb[0]; *(uint4*)&dl[8] = *(uint4*)&lb[8];
    }
}

// ---------------- prep3: epilogue vectors cvec/dvec ----------------
__global__ __launch_bounds__(256) void prep3_kernel(
    const float* __restrict__ scal,
    const float* __restrict__ csd, const float* __restrict__ css, const float* __restrict__ csb,
    const float* __restrict__ bc,
    float* __restrict__ cv, float* __restrict__ dv)
{
    int i = blockIdx.x;
    for (int j = threadIdx.x; j < 448; j += 256) {
        float c = 0.f, d = 0.f;
        if (j < 400) {
            const float* cs1 = (i==0) ? csd : csb;
            c = scal[i*8+1]*cs1[j] + scal[i*8+3]*css[j];
            d = scal[i*8+4]*bc[i*5*400 + j] + scal[i*8+5];
        }
        cv[i*448 + j] = c;
        dv[i*448 + j] = d;
    }
}

// ---------------- embed: node0/node1 bf16 hi/lo planes (padded strides) ----------------
__global__ __launch_bounds__(256) void embed_kernel(
    const float* __restrict__ rd, const int* __restrict__ rs,
    const float* __restrict__ emb,
    unsigned short* __restrict__ n0h, unsigned short* __restrict__ n0l,
    unsigned short* __restrict__ n1h, unsigned short* __restrict__ n1l,
    float* __restrict__ partial)
{
    int tid0 = blockIdx.x*256 + threadIdx.x;
    int nth = gridDim.x*256;
    float ssq = 0.f, dsq = 0.f;
    for (int it = tid0; it < 8192*26; it += nth) {
        int b = it / 26, s = it - b*26;
        int row = 13 + 50000*s + rs[b*26 + s];
        const float* e = emb + (size_t)row*16;
        float4 e0 = *(const float4*)&e[0], e1 = *(const float4*)&e[4];
        float4 e2 = *(const float4*)&e[8], e3 = *(const float4*)&e[12];
        float vv[16] = {e0.x,e0.y,e0.z,e0.w, e1.x,e1.y,e1.z,e1.w,
                        e2.x,e2.y,e2.z,e2.w, e3.x,e3.y,e3.z,e3.w};
        unsigned short hb[16], lb[16];
        for (int j = 0; j < 16; ++j) { ssq += vv[j]*vv[j]; split2(vv[j], hb[j], lb[j]); }
        size_t off = (size_t)b*SN1 + s*16;
        *(uint4*)&n1h[off] = *(uint4*)&hb[0]; *(uint4*)&n1h[off+8] = *(uint4*)&hb[8];
        *(uint4*)&n1l[off] = *(uint4*)&lb[0]; *(uint4*)&n1l[off+8] = *(uint4*)&lb[8];
    }
    for (int it = tid0; it < 8192*13; it += nth) {
        int b = it / 13, f = it - b*13;
        float sc = rd[b*13 + f];
        const float* e = emb + (size_t)f*16;
        float4 e0 = *(const float4*)&e[0], e1 = *(const float4*)&e[4];
        float4 e2 = *(const float4*)&e[8], e3 = *(const float4*)&e[12];
        float vv[16] = {e0.x,e0.y,e0.z,e0.w, e1.x,e1.y,e1.z,e1.w,
                        e2.x,e2.y,e2.z,e2.w, e3.x,e3.y,e3.z,e3.w};
        unsigned short hb[16], lb[16];
        for (int j = 0; j < 16; ++j) { float v = vv[j]*sc; dsq += v*v; split2(v, hb[j], lb[j]); }
        size_t off = (size_t)b*SN0 + f*16;
        *(uint4*)&n0h[off] = *(uint4*)&hb[0]; *(uint4*)&n0h[off+8] = *(uint4*)&hb[8];
        *(uint4*)&n0l[off] = *(uint4*)&lb[0]; *(uint4*)&n0l[off+8] = *(uint4*)&lb[8];
    }
    for (int o = 32; o > 0; o >>= 1) { ssq += __shfl_down(ssq, o); dsq += __shfl_down(dsq, o); }
    __shared__ float red[8];
    int wave = threadIdx.x >> 6, lane = threadIdx.x & 63;
    if (lane == 0) { red[wave] = dsq; red[4+wave] = ssq; }
    __syncthreads();
    if (threadIdx.x == 0) {
        partial[blockIdx.x*2]   = red[0]+red[1]+red[2]+red[3];
        partial[blockIdx.x*2+1] = red[4]+red[5]+red[6]+red[7];
    }
}

__global__ __launch_bounds__(256) void finalize_kernel(
    const float* __restrict__ clf_b, const float* __restrict__ partial, float* __restrict__ out)
{
    if (blockIdx.x < 32) {
        out[blockIdx.x*256 + threadIdx.x] = clf_b[0];
        return;
    }
    float d = 0.f, s = 0.f;
    for (int i = threadIdx.x; i < EMB_BLOCKS; i += 256) { d += partial[2*i]; s += partial[2*i+1]; }
    for (int o = 32; o > 0; o >>= 1) { d += __shfl_down(d, o); s += __shfl_down(s, o); }
    __shared__ float red[8];
    int wave = threadIdx.x >> 6, lane = threadIdx.x & 63;
    if (lane == 0) { red[wave] = d; red[4+wave] = s; }
    __syncthreads();
    if (threadIdx.x == 0) {
        float dd = red[0]+red[1]+red[2]+red[3];
        float ss = red[4]+red[5]+red[6]+red[7];
        out[8192] = 1e-5f * (sqrtf(dd) + sqrtf(ss));
    }
}

// ---------------- split-bf16 MFMA GEMM, 4-way K-split ----------------
// 896 blocks (XCD swizzle) x 4 waves. One 64x64 C-tile per block; wave w does
// k16 steps {w, w+4, ...} with direct-from-global fragment loads; partials
// combined via padded LDS (red[4][64][33], conflict-free) in 2 rounds.
__global__ __launch_bounds__(256, 3) void mfma_gemm(
    const unsigned short* __restrict__ a1h, const unsigned short* __restrict__ a1l, int sA, int KA,
    const unsigned short* __restrict__ a2h, const unsigned short* __restrict__ a2l,
    const unsigned short* __restrict__ bph, int Kp, int Kw,
    const float* __restrict__ vec, int relu,
    unsigned short* __restrict__ ch, unsigned short* __restrict__ cl,
    const float* __restrict__ lw, float* __restrict__ lout)
{
    __shared__ float red[4][64][33];   // padded: bank = (lane+j)%32, conflict-free
    int f = blockIdx.x;
    int xcd = f & 7, idx = f >> 3;          // 112 per XCD = 16 y-tiles x 7 x-tiles
    int yq = idx / 7;
    int ytile = xcd*16 + yq;
    int xtile = idx - yq*7;
    int bm = ytile*64, bn = xtile*64;
    int w = threadIdx.x >> 6, lane = threadIdx.x & 63;
    int r31 = lane & 31, hh = lane >> 5;
    int khalf = hh*8;

    const unsigned short* A1h = a1h + (size_t)(bm + r31)*sA + khalf;
    const unsigned short* A1l = a1l + (size_t)(bm + r31)*sA + khalf;
    const unsigned short* A2h = a2h + (size_t)(bm + r31)*SN1 + khalf;
    const unsigned short* A2l = a2l + (size_t)(bm + r31)*SN1 + khalf;
    const unsigned short* Bh  = bph + (size_t)(bn + r31)*Kw + khalf;
    const unsigned short* Bl  = Bh + (size_t)448*Kw;

    floatx16 acc00, acc01, acc10, acc11;
    for (int i = 0; i < 16; ++i) { acc00[i]=0.f; acc01[i]=0.f; acc10[i]=0.f; acc11[i]=0.f; }

    short8 xah0,xah1,xal0,xal1,xbh0,xbh1,xbl0,xbl1;
    short8 yah0,yah1,yal0,yal1,ybh0,ybh1,ybl0,ybl1;

    #define LOADF(P,ah0_,ah1_,al0_,al1_,bh0_,bh1_,bl0_,bl1_) do {              \
        int kb = (P);                                                          \
        if (kb < KA) {                                                         \
            ah0_ = *(const short8*)(A1h + kb);                                 \
            ah1_ = *(const short8*)(A1h + 32*sA + kb);                         \
            al0_ = *(const short8*)(A1l + kb);                                 \
            al1_ = *(const short8*)(A1l + 32*sA + kb);                         \
        } else {                                                               \
            int kc = kb - KA;                                                  \
            ah0_ = *(const short8*)(A2h + kc);                                 \
            ah1_ = *(const short8*)(A2h + 32*SN1 + kc);                        \
            al0_ = *(const short8*)(A2l + kc);                                 \
            al1_ = *(const short8*)(A2l + 32*SN1 + kc);                        \
        }                                                                      \
        bh0_ = *(const short8*)(Bh + kb);                                      \
        bh1_ = *(const short8*)(Bh + 32*Kw + kb);                              \
        bl0_ = *(const short8*)(Bl + kb);                                      \
        bl1_ = *(const short8*)(Bl + 32*Kw + kb);                              \
    } while(0)

    #define MFMAS(ah0_,ah1_,al0_,al1_,bh0_,bh1_,bl0_,bl1_) do {                \
        acc00 = __builtin_amdgcn_mfma_f32_32x32x16_bf16(ah0_, bh0_, acc00,0,0,0); \
        acc01 = __builtin_amdgcn_mfma_f32_32x32x16_bf16(ah0_, bh1_, acc01,0,0,0); \
        acc10 = __builtin_amdgcn_mfma_f32_32x32x16_bf16(ah1_, bh0_, acc10,0,0,0); \
        acc11 = __builtin_amdgcn_mfma_f32_32x32x16_bf16(ah1_, bh1_, acc11,0,0,0); \
        acc00 = __builtin_amdgcn_mfma_f32_32x32x16_bf16(ah0_, bl0_, acc00,0,0,0); \
        acc01 = __builtin_amdgcn_mfma_f32_32x32x16_bf16(ah0_, bl1_, acc01,0,0,0); \
        acc10 = __builtin_amdgcn_mfma_f32_32x32x16_bf16(ah1_, bl0_, acc10,0,0,0); \
        acc11 = __builtin_amdgcn_mfma_f32_32x32x16_bf16(ah1_, bl1_, acc11,0,0,0); \
        acc00 = __builtin_amdgcn_mfma_f32_32x32x16_bf16(al0_, bh0_, acc00,0,0,0); \
        acc01 = __builtin_amdgcn_mfma_f32_32x32x16_bf16(al0_, bh1_, acc01,0,0,0); \
        acc10 = __builtin_amdgcn_mfma_f32_32x32x16_bf16(al1_, bh0_, acc10,0,0,0); \
        acc11 = __builtin_amdgcn_mfma_f32_32x32x16_bf16(al1_, bh1_, acc11,0,0,0); \
    } while(0)

    int nk = Kp >> 4;
    int kidx = w;
    if (kidx < nk) {
        LOADF(kidx<<4, xah0,xah1,xal0,xal1,xbh0,xbh1,xbl0,xbl1);
        while (true) {
            int kn = kidx + 4;
            if (kn < nk) LOADF(kn<<4, yah0,yah1,yal0,yal1,ybh0,ybh1,ybl0,ybl1);
            MFMAS(xah0,xah1,xal0,xal1,xbh0,xbh1,xbl0,xbl1);
            kidx = kn; if (kidx >= nk) break;
            kn = kidx + 4;
            if (kn < nk) LOADF(kn<<4, xah0,xah1,xal0,xal1,xbh0,xbh1,xbl0,xbl1);
            MFMAS(yah0,yah1,yal0,yal1,ybh0,ybh1,ybl0,ybl1);
            kidx = kn; if (kidx >= nk) break;
        }
    }
    #undef LOADF
    #undef MFMAS

    // reduce partials + epilogue, 2 rounds (m-half = round)
    #pragma unroll
    for (int round = 0; round < 2; ++round) {
        const floatx16& aq0 = round == 0 ? acc00 : acc10;
        const floatx16& aq1 = round == 0 ? acc01 : acc11;
        #pragma unroll
        for (int j = 0; j < 16; ++j) {
            red[w][lane][j]      = aq0[j];
            red[w][lane][16 + j] = aq1[j];
        }
        __syncthreads();
        #pragma unroll
        for (int u = 0; u < 8; ++u) {
            int jj = w*8 + u;
            float v = red[0][lane][jj] + red[1][lane][jj]
                    + red[2][lane][jj] + red[3][lane][jj];
            int qq = jj >> 4, r = jj & 15;
            int gn = bn + qq*32 + r31;
            bool ok = gn < 400;
            int gm = bm + round*32 + (r & 3) + 8*(r >> 2) + 4*hh;
            v += ok ? vec[gn] : 0.f;
            if (relu) v = fmaxf(v, 0.f);
            if (ok) {
                unsigned short h16, l16;
                split2(v, h16, l16);
                ch[(size_t)gm*SH + gn] = h16;
                cl[(size_t)gm*SH + gn] = l16;
            }
            if (lw) {
                float lv = ok ? v * lw[gn] : 0.f;
                #pragma unroll
                for (int o = 1; o < 32; o <<= 1) lv += __shfl_xor(lv, o);
                if (r31 == 0) atomicAdd(&lout[gm], lv);
            }
        }
        __syncthreads();
    }
}

// ---------------- host ----------------
static inline size_t align64(size_t x) { return (x + 63) & ~(size_t)63; }

extern "C" void kernel_launch(void* const* d_in, const int* in_sizes, int n_in,
                              void* d_out, int out_size, void* d_ws, size_t ws_size,
                              hipStream_t stream)
{
    const float* raw_dense  = (const float*)d_in[0];
    const int*   raw_sparse = (const int*)d_in[1];
    const float* emb   = (const float*)d_in[2];
    const float* Pd    = (const float*)d_in[3];
    const float* Ps    = (const float*)d_in[4];
    const float* Pb    = (const float*)d_in[5];
    const float* Wc    = (const float*)d_in[6];
    const float* bc    = (const float*)d_in[7];
    const float* clf_w = (const float*)d_in[8];
    const float* clf_b = (const float*)d_in[9];
    const float* a0 = (const float*)d_in[10];
    const float* a1 = (const float*)d_in[11];
    const float* a2 = (const float*)d_in[12];
    const float* a3 = (const float*)d_in[13];
    float* out = (float*)d_out;

    char* p = (char*)d_ws;
    auto alloc = [&](size_t bytes) { char* r = p; p += align64(bytes); return r; };

    float* scal    = (float*)alloc(32*4);
    float* partial = (float*)alloc(2*EMB_BLOCKS*4);
    float* csd     = (float*)alloc(400*4);
    float* css     = (float*)alloc(400*4);
    float* csb     = (float*)alloc(400*4);
    float* cv      = (float*)alloc(4*448*4);
    float* dv      = (float*)alloc(4*448*4);
    unsigned short* w0 = (unsigned short*)alloc((size_t)2*448*640*2);
    unsigned short* w1 = (unsigned short*)alloc((size_t)2*448*832*2);
    unsigned short* w2 = (unsigned short*)alloc((size_t)2*448*832*2);
    unsigned short* w3 = (unsigned short*)alloc((size_t)2*448*832*2);
    unsigned short* v0 = (unsigned short*)alloc((size_t)2*448*416*2);
    unsigned short* v1 = (unsigned short*)alloc((size_t)2*448*416*2);
    unsigned short* v2 = (unsigned short*)alloc((size_t)2*448*416*2);
    unsigned short* v3 = (unsigned short*)alloc((size_t)2*448*416*2);
    unsigned short* n0h = (unsigned short*)alloc((size_t)8192*SN0*2);
    unsigned short* n0l = (unsigned short*)alloc((size_t)8192*SN0*2);
    unsigned short* n1h = (unsigned short*)alloc((size_t)8192*SN1*2);
    unsigned short* n1l = (unsigned short*)alloc((size_t)8192*SN1*2);
    unsigned short* hh  = (unsigned short*)alloc((size_t)8192*SH*2);
    unsigned short* hl  = (unsigned short*)alloc((size_t)8192*SH*2);
    unsigned short* nAh = (unsigned short*)alloc((size_t)8192*SH*2);
    unsigned short* nAl = (unsigned short*)alloc((size_t)8192*SH*2);
    unsigned short* nBh = (unsigned short*)alloc((size_t)8192*SH*2);
    unsigned short* nBl = (unsigned short*)alloc((size_t)8192*SH*2);

    prep1_kernel<<<5,256,0,stream>>>(Pd,Ps,Pb,a0,a1,a2,a3,scal,csd,css,csb);
    embed_kernel<<<EMB_BLOCKS,256,0,stream>>>(raw_dense, raw_sparse, emb, n0h,n0l,n1h,n1l, partial);
    finalize_kernel<<<33,256,0,stream>>>(clf_b, partial, out);
    prep2_kernel<<<dim3(7,13,8),256,0,stream>>>(Pd,Ps,Pb,Wc,scal,w0,w1,w2,w3,v0,v1,v2,v3);
    prep3_kernel<<<4,256,0,stream>>>(scal,csd,css,csb,bc,cv,dv);

    // block 0: h = relu([node0|node1] @ w0 + cv0); node2 = h @ v0 + dv0 (+logits)
    mfma_gemm<<<896,256,0,stream>>>(n0h,n0l,SN0,208, n1h,n1l, w0, 624,640, cv+0,    1, hh,hl,  nullptr,    nullptr);
    mfma_gemm<<<896,256,0,stream>>>(hh,hl,SH,400,    n1h,n1l, v0, 400,416, dv+0,    0, nAh,nAl, clf_w,      out);
    // block 1
    mfma_gemm<<<896,256,0,stream>>>(nAh,nAl,SH,400,  n1h,n1l, w1, 816,832, cv+448,  1, hh,hl,  nullptr,    nullptr);
    mfma_gemm<<<896,256,0,stream>>>(hh,hl,SH,400,    n1h,n1l, v1, 400,416, dv+448,  0, nBh,nBl, clf_w+400,  out);
    // block 2
    mfma_gemm<<<896,256,0,stream>>>(nBh,nBl,SH,400,  n1h,n1l, w2, 816,832, cv+896,  1, hh,hl,  nullptr,    nullptr);
    mfma_gemm<<<896,256,0,stream>>>(hh,hl,SH,400,    n1h,n1l, v2, 400,416, dv+896,  0, nAh,nAl, clf_w+800,  out);
    // block 3
    mfma_gemm<<<896,256,0,stream>>>(nAh,nAl,SH,400,  n1h,n1l, w3, 816,832, cv+1344, 1, hh,hl,  nullptr,    nullptr);
    mfma_gemm<<<896,256,0,stream>>>(hh,hl,SH,400,    n1h,n1l, v3, 400,416, dv+1344, 0, nBh,nBl, clf_w+1200, out);
}

// Round 7
// 488.953 us; speedup vs baseline: 1.1222x; 1.1222x over previous
//
#include <hip/hip_runtime.h>
#include <cstddef>

// DynamicNetwork via split-bf16 MFMA (hi/lo, 3 MFMA per product).
// R7: LDS-staged GEMM, 128x128 block tile, 8 waves (2m x 2n x 2 k-split),
// wave tile 64x64 (4 accs) -> 2x better LDS-bytes/FLOP than R3/R6.
// k16 double-buffered LDS, 2-chunk global prefetch, 1 barrier per k16.

typedef short short8 __attribute__((ext_vector_type(8)));
typedef float floatx16 __attribute__((ext_vector_type(16)));

#define EMB_BLOCKS 832
// padded strides (elements)
#define SN0 224   // node0 k-stride (208 used)
#define SN1 448   // node1 k-stride (416 used)
#define SH  416   // hidden/node k-stride (400 used)

__device__ __forceinline__ unsigned short f2bf(float f) {
    unsigned int u = __float_as_uint(f);
    u += 0x7fffu + ((u >> 16) & 1u);
    return (unsigned short)(u >> 16);
}
__device__ __forceinline__ float bf2f(unsigned short h) {
    return __uint_as_float((unsigned int)h << 16);
}
__device__ __forceinline__ void split2(float v, unsigned short& h, unsigned short& l) {
    h = f2bf(v);
    l = f2bf(v - bf2f(h));
}

// ---------------- prep1: column sums + alpha scalars ----------------
__global__ __launch_bounds__(256) void prep1_kernel(
    const float* __restrict__ Pd, const float* __restrict__ Ps, const float* __restrict__ Pb,
    const float* __restrict__ a0, const float* __restrict__ a1,
    const float* __restrict__ a2, const float* __restrict__ a3,
    float* __restrict__ scal,
    float* __restrict__ csd, float* __restrict__ css, float* __restrict__ csb)
{
    int gid = blockIdx.x * 256 + threadIdx.x;
    if (gid < 400) {
        float s = 0.f;
        for (int k = 0; k < 208; ++k) s += Pd[k*400 + gid];
        csd[gid] = s;
    } else if (gid < 800) {
        int j = gid - 400; float s = 0.f;
        for (int k = 0; k < 416; ++k) s += Ps[k*400 + j];
        css[j] = s;
    } else if (gid < 1200) {
        int j = gid - 800; float s = 0.f;
        for (int k = 0; k < 400; ++k) s += Pb[k*400 + j];
        csb[j] = s;
    } else if (gid < 1204) {
        int i = gid - 1200;
        const float* a = (i==0) ? a0 : (i==1) ? a1 : (i==2) ? a2 : a3;
        int np = 2 + i;
        float sum1 = 0.f, sum2 = 0.f, sumc = 0.f;
        for (int j = 0; j < np; ++j) { sum1 += a[j]; sum2 += a[np+j]; }
        for (int j = 0; j < 4; ++j) sumc += a[2*np+j];
        int i1 = (i==0) ? 0 : 1;
        int i2 = i + 1;
        int kk = i;
        float s1 = a[i1],      c1 = sum1 - s1;
        float s2 = a[np+i2],   c2 = sum2 - s2;
        float sk = a[2*np+kk], ck = sumc - sk;
        float* sl = scal + i*8;
        if (i == 0) { sl[0]=s1; sl[1]=c1; sl[2]=s2; sl[3]=c2; }
        else        { sl[0]=s2; sl[1]=c2; sl[2]=s1; sl[3]=c1; }
        sl[4] = sk; sl[5] = ck;
    }
}

// ---------------- prep2: transpose + scale + split weights -> [2][512][Kw] bf16 planes
__global__ __launch_bounds__(256) void prep2_kernel(
    const float* __restrict__ Pd, const float* __restrict__ Ps,
    const float* __restrict__ Pb, const float* __restrict__ Wc,
    const float* __restrict__ scal,
    unsigned short* __restrict__ w0, unsigned short* __restrict__ w1,
    unsigned short* __restrict__ w2, unsigned short* __restrict__ w3,
    unsigned short* __restrict__ v0, unsigned short* __restrict__ v1,
    unsigned short* __restrict__ v2, unsigned short* __restrict__ v3)
{
    int z = blockIdx.z;
    int Kp, KA, Kw; const float *sA, *sB; float sc1, sc2; unsigned short* dst;
    if (z < 4) {
        Kp = (z==0) ? 624 : 816; KA = (z==0) ? 208 : 400; Kw = (z==0) ? 640 : 832;
        sA = (z==0) ? Pd : Pb; sB = Ps;
        sc1 = scal[z*8+0]; sc2 = scal[z*8+2];
        dst = (z==0) ? w0 : (z==1) ? w1 : (z==2) ? w2 : w3;
    } else {
        int i = z - 4;
        Kp = 400; KA = 400; Kw = 416;
        sA = Wc + (size_t)i*5*160000; sB = nullptr;
        sc1 = scal[i*8+4]; sc2 = 0.f;
        dst = (i==0) ? v0 : (i==1) ? v1 : (i==2) ? v2 : v3;
    }
    int ktiles = (Kp + 63) >> 6;
    if ((int)blockIdx.y >= ktiles) return;
    int k0 = blockIdx.y * 64, n0 = blockIdx.x * 64;
    __shared__ float T[64][65];
    int t = threadIdx.x;
    {
        int kr = t >> 2, c0 = (t & 3) * 16;
        int gk = k0 + kr;
        bool kok = gk < Kp;
        const float* src; int srow; float sc;
        if (gk < KA) { src = sA; srow = gk; sc = sc1; }
        else         { src = sB; srow = gk - KA; sc = sc2; }
        for (int j = 0; j < 16; j += 4) {
            int n = n0 + c0 + j;
            float4 v = make_float4(0.f,0.f,0.f,0.f);
            if (kok && n < 400) v = *(const float4*)&src[(size_t)srow*400 + n];
            T[kr][c0+j+0] = v.x * sc;
            T[kr][c0+j+1] = v.y * sc;
            T[kr][c0+j+2] = v.z * sc;
            T[kr][c0+j+3] = v.w * sc;
        }
    }
    __syncthreads();
    {
        int nr = t >> 2, kc0 = (t & 3) * 16;
        int gn = n0 + nr;
        int gk0 = k0 + kc0;
        if (gk0 >= Kp) return;
        unsigned short hb[16], lb[16];
        for (int j = 0; j < 16; ++j) {
            float v = (gn < 400) ? T[kc0+j][nr] : 0.f;
            split2(v, hb[j], lb[j]);
        }
        unsigned short* dh = dst + (size_t)gn*Kw + gk0;
        unsigned short* dl = dst + (size_t)512*Kw + (size_t)gn*Kw + gk0;
        *(uint4*)&dh[0] = *(uint4*)&hb[0]; *(uint4*)&dh[8] = *(uint4*)&hb[8];
        *(uint4*)&dl[0] = *(uint4*)&lb[0]; *(uint4*)&dl[8] = *(uint4*)&lb[8];
    }
}

// ---------------- prep3: epilogue vectors cvec/dvec ----------------
__global__ __launch_bounds__(256) void prep3_kernel(
    const float* __restrict__ scal,
    const float* __restrict__ csd, const float* __restrict__ css, const float* __restrict__ csb,
    const float* __restrict__ bc,
    float* __restrict__ cv, float* __restrict__ dv)
{
    int i = blockIdx.x;
    for (int j = threadIdx.x; j < 448; j += 256) {
        float c = 0.f, d = 0.f;
        if (j < 400) {
            const float* cs1 = (i==0) ? csd : csb;
            c = scal[i*8+1]*cs1[j] + scal[i*8+3]*css[j];
            d = scal[i*8+4]*bc[i*5*400 + j] + scal[i*8+5];
        }
        cv[i*448 + j] = c;
        dv[i*448 + j] = d;
    }
}

// ---------------- embed: node0/node1 bf16 hi/lo planes (padded strides) ----------------
__global__ __launch_bounds__(256) void embed_kernel(
    const float* __restrict__ rd, const int* __restrict__ rs,
    const float* __restrict__ emb,
    unsigned short* __restrict__ n0h, unsigned short* __restrict__ n0l,
    unsigned short* __restrict__ n1h, unsigned short* __restrict__ n1l,
    float* __restrict__ partial)
{
    int tid0 = blockIdx.x*256 + threadIdx.x;
    int nth = gridDim.x*256;
    float ssq = 0.f, dsq = 0.f;
    for (int it = tid0; it < 8192*26; it += nth) {
        int b = it / 26, s = it - b*26;
        int row = 13 + 50000*s + rs[b*26 + s];
        const float* e = emb + (size_t)row*16;
        float4 e0 = *(const float4*)&e[0], e1 = *(const float4*)&e[4];
        float4 e2 = *(const float4*)&e[8], e3 = *(const float4*)&e[12];
        float vv[16] = {e0.x,e0.y,e0.z,e0.w, e1.x,e1.y,e1.z,e1.w,
                        e2.x,e2.y,e2.z,e2.w, e3.x,e3.y,e3.z,e3.w};
        unsigned short hb[16], lb[16];
        for (int j = 0; j < 16; ++j) { ssq += vv[j]*vv[j]; split2(vv[j], hb[j], lb[j]); }
        size_t off = (size_t)b*SN1 + s*16;
        *(uint4*)&n1h[off] = *(uint4*)&hb[0]; *(uint4*)&n1h[off+8] = *(uint4*)&hb[8];
        *(uint4*)&n1l[off] = *(uint4*)&lb[0]; *(uint4*)&n1l[off+8] = *(uint4*)&lb[8];
    }
    for (int it = tid0; it < 8192*13; it += nth) {
        int b = it / 13, f = it - b*13;
        float sc = rd[b*13 + f];
        const float* e = emb + (size_t)f*16;
        float4 e0 = *(const float4*)&e[0], e1 = *(const float4*)&e[4];
        float4 e2 = *(const float4*)&e[8], e3 = *(const float4*)&e[12];
        float vv[16] = {e0.x,e0.y,e0.z,e0.w, e1.x,e1.y,e1.z,e1.w,
                        e2.x,e2.y,e2.z,e2.w, e3.x,e3.y,e3.z,e3.w};
        unsigned short hb[16], lb[16];
        for (int j = 0; j < 16; ++j) { float v = vv[j]*sc; dsq += v*v; split2(v, hb[j], lb[j]); }
        size_t off = (size_t)b*SN0 + f*16;
        *(uint4*)&n0h[off] = *(uint4*)&hb[0]; *(uint4*)&n0h[off+8] = *(uint4*)&hb[8];
        *(uint4*)&n0l[off] = *(uint4*)&lb[0]; *(uint4*)&n0l[off+8] = *(uint4*)&lb[8];
    }
    for (int o = 32; o > 0; o >>= 1) { ssq += __shfl_down(ssq, o); dsq += __shfl_down(dsq, o); }
    __shared__ float red[8];
    int wave = threadIdx.x >> 6, lane = threadIdx.x & 63;
    if (lane == 0) { red[wave] = dsq; red[4+wave] = ssq; }
    __syncthreads();
    if (threadIdx.x == 0) {
        partial[blockIdx.x*2]   = red[0]+red[1]+red[2]+red[3];
        partial[blockIdx.x*2+1] = red[4]+red[5]+red[6]+red[7];
    }
}

__global__ __launch_bounds__(256) void finalize_kernel(
    const float* __restrict__ clf_b, const float* __restrict__ partial, float* __restrict__ out)
{
    if (blockIdx.x < 32) {
        out[blockIdx.x*256 + threadIdx.x] = clf_b[0];
        return;
    }
    float d = 0.f, s = 0.f;
    for (int i = threadIdx.x; i < EMB_BLOCKS; i += 256) { d += partial[2*i]; s += partial[2*i+1]; }
    for (int o = 32; o > 0; o >>= 1) { d += __shfl_down(d, o); s += __shfl_down(s, o); }
    __shared__ float red[8];
    int wave = threadIdx.x >> 6, lane = threadIdx.x & 63;
    if (lane == 0) { red[wave] = d; red[4+wave] = s; }
    __syncthreads();
    if (threadIdx.x == 0) {
        float dd = red[0]+red[1]+red[2]+red[3];
        float ss = red[4]+red[5]+red[6]+red[7];
        out[8192] = 1e-5f * (sqrtf(dd) + sqrtf(ss));
    }
}

// ---------------- LDS-staged split-bf16 MFMA GEMM ----------------
// 256 blocks (64 m x 4 n tiles of 128, XCD swizzle), 512 threads = 8 waves
// (mw,nw,kw): wave tile 64x64 (4 accs), k16 steps of parity kw.
// LDS lds[A/B][buf][plane][128][24] shorts = 48 KB, double-buffered.
__global__ __launch_bounds__(512, 2) void mfma_gemm(
    const unsigned short* __restrict__ a1h, const unsigned short* __restrict__ a1l, int sA, int KA,
    const unsigned short* __restrict__ a2h, const unsigned short* __restrict__ a2l,
    const unsigned short* __restrict__ bph, int Kp, int Kw,
    const float* __restrict__ vec, int relu,
    unsigned short* __restrict__ ch, unsigned short* __restrict__ cl,
    const float* __restrict__ lw, float* __restrict__ lout)
{
    __shared__ __align__(16) unsigned short lds[2][2][2][128][24];
    const int BUFS = 2*128*24;   // shorts: buf stride within A or B region
    const int PL   = 128*24;     // plane stride
    const int R32  = 32*24;      // 32-row stride

    int tid = threadIdx.x;
    int bid = blockIdx.x;
    int xcd = bid & 7, idx = bid >> 3;    // 32 blocks/XCD: 8 m-tiles x 4 n-tiles
    int mt = xcd*8 + (idx >> 2);
    int nt = idx & 3;
    int bm = mt * 128, bn = nt * 128;

    int W = tid >> 6, lane = tid & 63;
    int kw = W & 1, nw = (W >> 1) & 1, mw = W >> 2;
    int r31 = lane & 31, hh = lane >> 5;

    // staging: thread -> (plane, row/col, k-half)
    int sp  = tid >> 8;
    int srr = (tid >> 1) & 127;
    int sh8 = (tid & 1) * 8;

    const unsigned short* Arow1 = (sp ? a1l : a1h) + (size_t)(bm + srr)*sA + sh8;
    const unsigned short* Arow2 = (sp ? a2l : a2h) + (size_t)(bm + srr)*SN1 + sh8 - KA;
    const unsigned short* Brow  = bph + (size_t)sp*512*Kw + (size_t)(bn + srr)*Kw + sh8;

    unsigned short* wA = &lds[0][0][sp][srr][sh8];
    unsigned short* wB = &lds[1][0][sp][srr][sh8];
    const unsigned short* fA = &lds[0][0][0][mw*64 + r31][hh*8];
    const unsigned short* fB = &lds[1][0][0][nw*64 + r31][hh*8];

    int nk = Kp >> 4;

    floatx16 acc00, acc01, acc10, acc11;   // [m-frag][n-frag]
    for (int i = 0; i < 16; ++i) { acc00[i]=0.f; acc01[i]=0.f; acc10[i]=0.f; acc11[i]=0.f; }

    #define GLOAD(K, AV, BV) do {                                              \
        int kb_ = (K) << 4;                                                    \
        AV = (kb_ < KA) ? *(const uint4*)(Arow1 + kb_)                         \
                        : *(const uint4*)(Arow2 + kb_);                        \
        BV = *(const uint4*)(Brow + kb_);                                      \
    } while(0)

    #define COMPUTE(BOFF) do {                                                 \
        const unsigned short* pa = fA + (BOFF);                                \
        const unsigned short* pb = fB + (BOFF);                                \
        short8 a0h = *(const short8*)(pa);                                     \
        short8 a1h_ = *(const short8*)(pa + R32);                              \
        short8 a0l = *(const short8*)(pa + PL);                                \
        short8 a1l_ = *(const short8*)(pa + PL + R32);                         \
        short8 b0h = *(const short8*)(pb);                                     \
        short8 b1h = *(const short8*)(pb + R32);                               \
        short8 b0l = *(const short8*)(pb + PL);                                \
        short8 b1l = *(const short8*)(pb + PL + R32);                          \
        acc00 = __builtin_amdgcn_mfma_f32_32x32x16_bf16(a0h, b0h, acc00,0,0,0);\
        acc01 = __builtin_amdgcn_mfma_f32_32x32x16_bf16(a0h, b1h, acc01,0,0,0);\
        acc10 = __builtin_amdgcn_mfma_f32_32x32x16_bf16(a1h_, b0h, acc10,0,0,0);\
        acc11 = __builtin_amdgcn_mfma_f32_32x32x16_bf16(a1h_, b1h, acc11,0,0,0);\
        acc00 = __builtin_amdgcn_mfma_f32_32x32x16_bf16(a0h, b0l, acc00,0,0,0);\
        acc01 = __builtin_amdgcn_mfma_f32_32x32x16_bf16(a0h, b1l, acc01,0,0,0);\
        acc10 = __builtin_amdgcn_mfma_f32_32x32x16_bf16(a1h_, b0l, acc10,0,0,0);\
        acc11 = __builtin_amdgcn_mfma_f32_32x32x16_bf16(a1h_, b1l, acc11,0,0,0);\
        acc00 = __builtin_amdgcn_mfma_f32_32x32x16_bf16(a0l, b0h, acc00,0,0,0);\
        acc01 = __builtin_amdgcn_mfma_f32_32x32x16_bf16(a0l, b1h, acc01,0,0,0);\
        acc10 = __builtin_amdgcn_mfma_f32_32x32x16_bf16(a1l_, b0h, acc10,0,0,0);\
        acc11 = __builtin_amdgcn_mfma_f32_32x32x16_bf16(a1l_, b1h, acc11,0,0,0);\
    } while(0)

    uint4 avA, bvA, avB, bvB;
    GLOAD(0, avA, bvA);
    if (nk > 1) GLOAD(1, avB, bvB);

    int k = 0;
    while (true) {
        // even chunk -> buf 0
        *(uint4*)(wA) = avA;
        *(uint4*)(wB) = bvA;
        __syncthreads();
        if (k + 2 < nk) GLOAD(k + 2, avA, bvA);
        if (kw == 0) COMPUTE(0);
        if (++k >= nk) break;
        // odd chunk -> buf 1
        *(uint4*)(wA + BUFS) = avB;
        *(uint4*)(wB + BUFS) = bvB;
        __syncthreads();
        if (k + 2 < nk) GLOAD(k + 2, avB, bvB);
        if (kw == 1) COMPUTE(BUFS);
        if (++k >= nk) break;
    }
    #undef GLOAD
    #undef COMPUTE

    __syncthreads();

    // k-split reduction via LDS (reuse staging memory): red[4][64][36] floats
    float* red = (float*)&lds[0][0][0][0][0];
    int wp = W >> 1;                      // wave-pair id (mw,nw)
    float* myred = red + (wp*64 + lane)*36;

    #pragma unroll
    for (int r = 0; r < 2; ++r) {
        const floatx16& aq0 = r ? acc10 : acc00;
        const floatx16& aq1 = r ? acc11 : acc01;
        if (kw == 1) {
            #pragma unroll
            for (int j4 = 0; j4 < 4; ++j4) {
                *(float4*)(myred + j4*4)      = make_float4(aq0[j4*4+0],aq0[j4*4+1],aq0[j4*4+2],aq0[j4*4+3]);
                *(float4*)(myred + 16 + j4*4) = make_float4(aq1[j4*4+0],aq1[j4*4+1],aq1[j4*4+2],aq1[j4*4+3]);
            }
        }
        __syncthreads();
        if (kw == 0) {
            int gn0 = bn + nw*64 + r31;
            int gn1 = gn0 + 32;
            bool ok0 = gn0 < 400, ok1 = gn1 < 400;
            float vc0 = ok0 ? vec[gn0] : 0.f;
            float vc1 = ok1 ? vec[gn1] : 0.f;
            float wv0 = (lw && ok0) ? lw[gn0] : 0.f;
            float wv1 = (lw && ok1) ? lw[gn1] : 0.f;
            #pragma unroll
            for (int j = 0; j < 16; ++j) {
                int gm = bm + mw*64 + r*32 + (j & 3) + 8*(j >> 2) + 4*hh;
                float v0 = aq0[j] + myred[j] + vc0;
                float v1 = aq1[j] + myred[16 + j] + vc1;
                if (relu) { v0 = fmaxf(v0, 0.f); v1 = fmaxf(v1, 0.f); }
                if (ok0) {
                    unsigned short h16, l16; split2(v0, h16, l16);
                    ch[(size_t)gm*SH + gn0] = h16;
                    cl[(size_t)gm*SH + gn0] = l16;
                }
                if (ok1) {
                    unsigned short h16, l16; split2(v1, h16, l16);
                    ch[(size_t)gm*SH + gn1] = h16;
                    cl[(size_t)gm*SH + gn1] = l16;
                }
                if (lw) {
                    float lv = v0*wv0 + v1*wv1;
                    #pragma unroll
                    for (int o = 1; o < 32; o <<= 1) lv += __shfl_xor(lv, o);
                    if (r31 == 0) atomicAdd(&lout[gm], lv);
                }
            }
        }
        __syncthreads();
    }
}

// ---------------- host ----------------
static inline size_t align64(size_t x) { return (x + 63) & ~(size_t)63; }

extern "C" void kernel_launch(void* const* d_in, const int* in_sizes, int n_in,
                              void* d_out, int out_size, void* d_ws, size_t ws_size,
                              hipStream_t stream)
{
    const float* raw_dense  = (const float*)d_in[0];
    const int*   raw_sparse = (const int*)d_in[1];
    const float* emb   = (const float*)d_in[2];
    const float* Pd    = (const float*)d_in[3];
    const float* Ps    = (const float*)d_in[4];
    const float* Pb    = (const float*)d_in[5];
    const float* Wc    = (const float*)d_in[6];
    const float* bc    = (const float*)d_in[7];
    const float* clf_w = (const float*)d_in[8];
    const float* clf_b = (const float*)d_in[9];
    const float* a0 = (const float*)d_in[10];
    const float* a1 = (const float*)d_in[11];
    const float* a2 = (const float*)d_in[12];
    const float* a3 = (const float*)d_in[13];
    float* out = (float*)d_out;

    char* p = (char*)d_ws;
    auto alloc = [&](size_t bytes) { char* r = p; p += align64(bytes); return r; };

    float* scal    = (float*)alloc(32*4);
    float* partial = (float*)alloc(2*EMB_BLOCKS*4);
    float* csd     = (float*)alloc(400*4);
    float* css     = (float*)alloc(400*4);
    float* csb     = (float*)alloc(400*4);
    float* cv      = (float*)alloc(4*448*4);
    float* dv      = (float*)alloc(4*448*4);
    unsigned short* w0 = (unsigned short*)alloc((size_t)2*512*640*2);
    unsigned short* w1 = (unsigned short*)alloc((size_t)2*512*832*2);
    unsigned short* w2 = (unsigned short*)alloc((size_t)2*512*832*2);
    unsigned short* w3 = (unsigned short*)alloc((size_t)2*512*832*2);
    unsigned short* v0 = (unsigned short*)alloc((size_t)2*512*416*2);
    unsigned short* v1 = (unsigned short*)alloc((size_t)2*512*416*2);
    unsigned short* v2 = (unsigned short*)alloc((size_t)2*512*416*2);
    unsigned short* v3 = (unsigned short*)alloc((size_t)2*512*416*2);
    unsigned short* n0h = (unsigned short*)alloc((size_t)8192*SN0*2);
    unsigned short* n0l = (unsigned short*)alloc((size_t)8192*SN0*2);
    unsigned short* n1h = (unsigned short*)alloc((size_t)8192*SN1*2);
    unsigned short* n1l = (unsigned short*)alloc((size_t)8192*SN1*2);
    unsigned short* hh  = (unsigned short*)alloc((size_t)8192*SH*2);
    unsigned short* hl  = (unsigned short*)alloc((size_t)8192*SH*2);
    unsigned short* nAh = (unsigned short*)alloc((size_t)8192*SH*2);
    unsigned short* nAl = (unsigned short*)alloc((size_t)8192*SH*2);
    unsigned short* nBh = (unsigned short*)alloc((size_t)8192*SH*2);
    unsigned short* nBl = (unsigned short*)alloc((size_t)8192*SH*2);

    prep1_kernel<<<5,256,0,stream>>>(Pd,Ps,Pb,a0,a1,a2,a3,scal,csd,css,csb);
    embed_kernel<<<EMB_BLOCKS,256,0,stream>>>(raw_dense, raw_sparse, emb, n0h,n0l,n1h,n1l, partial);
    finalize_kernel<<<33,256,0,stream>>>(clf_b, partial, out);
    prep2_kernel<<<dim3(8,13,8),256,0,stream>>>(Pd,Ps,Pb,Wc,scal,w0,w1,w2,w3,v0,v1,v2,v3);
    prep3_kernel<<<4,256,0,stream>>>(scal,csd,css,csb,bc,cv,dv);

    // block 0: h = relu([node0|node1] @ w0 + cv0); node2 = h @ v0 + dv0 (+logits)
    mfma_gemm<<<256,512,0,stream>>>(n0h,n0l,SN0,208, n1h,n1l, w0, 624,640, cv+0,    1, hh,hl,  nullptr,    nullptr);
    mfma_gemm<<<256,512,0,stream>>>(hh,hl,SH,400,    n1h,n1l, v0, 400,416, dv+0,    0, nAh,nAl, clf_w,      out);
    // block 1
    mfma_gemm<<<256,512,0,stream>>>(nAh,nAl,SH,400,  n1h,n1l, w1, 816,832, cv+448,  1, hh,hl,  nullptr,    nullptr);
    mfma_gemm<<<256,512,0,stream>>>(hh,hl,SH,400,    n1h,n1l, v1, 400,416, dv+448,  0, nBh,nBl, clf_w+400,  out);
    // block 2
    mfma_gemm<<<256,512,0,stream>>>(nBh,nBl,SH,400,  n1h,n1l, w2, 816,832, cv+896,  1, hh,hl,  nullptr,    nullptr);
    mfma_gemm<<<256,512,0,stream>>>(hh,hl,SH,400,    n1h,n1l, v2, 400,416, dv+896,  0, nAh,nAl, clf_w+800,  out);
    // block 3
    mfma_gemm<<<256,512,0,stream>>>(nAh,nAl,SH,400,  n1h,n1l, w3, 816,832, cv+1344, 1, hh,hl,  nullptr,    nullptr);
    mfma_gemm<<<256,512,0,stream>>>(hh,hl,SH,400,    n1h,n1l, v3, 400,416, dv+1344, 0, nBh,nBl, clf_w+1200, out);
}

// Round 8
// 450.681 us; speedup vs baseline: 1.2175x; 1.0849x over previous
//
#include <hip/hip_runtime.h>
#include <cstddef>

// DynamicNetwork via split-bf16 MFMA (hi/lo, 3 MFMA per product).
// R8: algebraic fusion — nodes 2..5 never materialized.
//   h_0 = relu([node0|node1] @ [s1 Pd; s2 Ps] + C_0)
//   h_i = relu([h_{i-1}|node1] @ [M_i; s1_i Ps] + C_i),  M_i = s2_i sk_{i-1} (Wc_{i-1}@Pb)
//   logits = sum_i h_i @ gv_i + const,                  gv_i = sk_i Wc_i @ clf_w_i
// 4 GEMMs instead of 8 (K-sum 4672 -> 3072); GEMM kernel = R7 128x128 LDS-staged.

typedef short short8 __attribute__((ext_vector_type(8)));
typedef float floatx16 __attribute__((ext_vector_type(16)));

#define EMB_BLOCKS 832
#define SN0 224   // node0 k-stride (208 used)
#define SN1 448   // node1 k-stride (416 used)
#define SH  416   // hidden k-stride (400 used)

__device__ __forceinline__ unsigned short f2bf(float f) {
    unsigned int u = __float_as_uint(f);
    u += 0x7fffu + ((u >> 16) & 1u);
    return (unsigned short)(u >> 16);
}
__device__ __forceinline__ float bf2f(unsigned short h) {
    return __uint_as_float((unsigned int)h << 16);
}
__device__ __forceinline__ void split2(float v, unsigned short& h, unsigned short& l) {
    h = f2bf(v);
    l = f2bf(v - bf2f(h));
}

// ---------------- prep1: column sums + alpha scalars ----------------
__global__ __launch_bounds__(256) void prep1_kernel(
    const float* __restrict__ Pd, const float* __restrict__ Ps, const float* __restrict__ Pb,
    const float* __restrict__ a0, const float* __restrict__ a1,
    const float* __restrict__ a2, const float* __restrict__ a3,
    float* __restrict__ scal,
    float* __restrict__ csd, float* __restrict__ css, float* __restrict__ csb)
{
    int gid = blockIdx.x * 256 + threadIdx.x;
    if (gid < 400) {
        float s = 0.f;
        for (int k = 0; k < 208; ++k) s += Pd[k*400 + gid];
        csd[gid] = s;
    } else if (gid < 800) {
        int j = gid - 400; float s = 0.f;
        for (int k = 0; k < 416; ++k) s += Ps[k*400 + j];
        css[j] = s;
    } else if (gid < 1200) {
        int j = gid - 800; float s = 0.f;
        for (int k = 0; k < 400; ++k) s += Pb[k*400 + j];
        csb[j] = s;
    } else if (gid < 1204) {
        int i = gid - 1200;
        const float* a = (i==0) ? a0 : (i==1) ? a1 : (i==2) ? a2 : a3;
        int np = 2 + i;
        float sum1 = 0.f, sum2 = 0.f, sumc = 0.f;
        for (int j = 0; j < np; ++j) { sum1 += a[j]; sum2 += a[np+j]; }
        for (int j = 0; j < 4; ++j) sumc += a[2*np+j];
        int i1 = (i==0) ? 0 : 1;
        int i2 = i + 1;
        int kk = i;
        float s1 = a[i1],      c1 = sum1 - s1;   // node1 (or node0) term
        float s2 = a[np+i2],   c2 = sum2 - s2;   // chained-node term
        float sk = a[2*np+kk], ck = sumc - sk;
        float* sl = scal + i*8;
        // layout: [0]=sA,[1]=cA (A-segment), [2]=sPs,[3]=cPs, [4]=sk,[5]=ck
        if (i == 0) { sl[0]=s1; sl[1]=c1; sl[2]=s2; sl[3]=c2; }
        else        { sl[0]=s2; sl[1]=c2; sl[2]=s1; sl[3]=c1; }
        sl[4] = sk; sl[5] = ck;
    }
}

// ---------------- prep2: Ps/Pd regions of weight planes [2][512][Kw] ----------------
// z=0: full [s1*Pd ; s2*Ps] (k<624).  z=1..3: only k in [400,816) = s1_z*Ps.
__global__ __launch_bounds__(256) void prep2_kernel(
    const float* __restrict__ Pd, const float* __restrict__ Ps,
    const float* __restrict__ Pb,
    const float* __restrict__ scal,
    unsigned short* __restrict__ w0, unsigned short* __restrict__ w1,
    unsigned short* __restrict__ w2, unsigned short* __restrict__ w3)
{
    int z = blockIdx.z;
    int Kp = (z==0) ? 624 : 816;
    int KA = (z==0) ? 208 : 400;
    int Kw = (z==0) ? 640 : 832;
    const float* sA = (z==0) ? Pd : Pb;
    const float* sB = Ps;
    float sc1 = scal[z*8+0];
    float sc2 = scal[z*8+2];
    unsigned short* dst = (z==0) ? w0 : (z==1) ? w1 : (z==2) ? w2 : w3;

    int ktiles = (Kp + 63) >> 6;
    if ((int)blockIdx.y >= ktiles) return;
    int k0 = blockIdx.y * 64, n0 = blockIdx.x * 64;
    __shared__ float T[64][65];
    int t = threadIdx.x;
    {
        int kr = t >> 2, c0 = (t & 3) * 16;
        int gk = k0 + kr;
        bool kok = gk < Kp;
        const float* src; int srow; float sc;
        if (gk < KA) { src = sA; srow = gk; sc = sc1; }
        else         { src = sB; srow = gk - KA; sc = sc2; }
        for (int j = 0; j < 16; j += 4) {
            int n = n0 + c0 + j;
            float4 v = make_float4(0.f,0.f,0.f,0.f);
            if (kok && n < 400) v = *(const float4*)&src[(size_t)srow*400 + n];
            T[kr][c0+j+0] = v.x * sc;
            T[kr][c0+j+1] = v.y * sc;
            T[kr][c0+j+2] = v.z * sc;
            T[kr][c0+j+3] = v.w * sc;
        }
    }
    __syncthreads();
    {
        int nr = t >> 2, kc0 = (t & 3) * 16;
        int gn = n0 + nr;
        int gk0 = k0 + kc0;
        if (gk0 >= Kp) return;
        if (z > 0 && gk0 < 400) return;   // M-region written by prepM
        unsigned short hb[16], lb[16];
        for (int j = 0; j < 16; ++j) {
            float v = (gn < 400) ? T[kc0+j][nr] : 0.f;
            split2(v, hb[j], lb[j]);
        }
        unsigned short* dh = dst + (size_t)gn*Kw + gk0;
        unsigned short* dl = dst + (size_t)512*Kw + (size_t)gn*Kw + gk0;
        *(uint4*)&dh[0] = *(uint4*)&hb[0]; *(uint4*)&dh[8] = *(uint4*)&hb[8];
        *(uint4*)&dl[0] = *(uint4*)&lb[0]; *(uint4*)&dl[8] = *(uint4*)&lb[8];
    }
}

// ---------------- prepM: M_g = s2_g * sk_{g-1} * (Wc_{g-1} @ Pb), g = z+1 ----------------
// fp32 64x64-tile GEMM; writes transposed+split into wgt planes [n][k], k<400.
__global__ __launch_bounds__(256) void prepM_kernel(
    const float* __restrict__ Wc, const float* __restrict__ Pb,
    const float* __restrict__ scal,
    unsigned short* __restrict__ w1, unsigned short* __restrict__ w2,
    unsigned short* __restrict__ w3)
{
    int z = blockIdx.z;                   // 0..2 -> GEMM g = z+1
    unsigned short* dst = (z==0) ? w1 : (z==1) ? w2 : w3;
    const float* A = Wc + (size_t)z*5*160000;   // Wc[z, kk=z] : [400k][400j]
    float scale = scal[(z+1)*8+0] * scal[z*8+4];
    const int Kw = 832;

    __shared__ float As[16][68];   // [j][k]
    __shared__ float Ws[16][68];   // [j][n]
    int t = threadIdx.x;
    int tx = t & 15, ty = t >> 4;
    int bk = blockIdx.y * 64;      // k tile (h-dim), 0..447
    int bn = blockIdx.x * 64;      // n tile, 0..511
    int arow = t >> 2;             // k index 0..63
    int aj4  = (t & 3) << 2;
    int wrow = t >> 4;             // j 0..15
    int wc4  = (t & 15) << 2;
    float acc[4][4] = {};
    for (int j0 = 0; j0 < 400; j0 += 16) {
        float4 av = make_float4(0.f,0.f,0.f,0.f);
        if (bk + arow < 400) av = *(const float4*)&A[(size_t)(bk+arow)*400 + j0 + aj4];
        float4 wv = make_float4(0.f,0.f,0.f,0.f);
        if (bn + wc4 < 400) wv = *(const float4*)&Pb[(size_t)(j0+wrow)*400 + bn + wc4];
        __syncthreads();
        As[aj4+0][arow] = av.x;
        As[aj4+1][arow] = av.y;
        As[aj4+2][arow] = av.z;
        As[aj4+3][arow] = av.w;
        *(float4*)&Ws[wrow][wc4] = wv;
        __syncthreads();
        #pragma unroll
        for (int jj = 0; jj < 16; ++jj) {
            float4 a4 = *(const float4*)&As[jj][ty<<2];
            float4 b4 = *(const float4*)&Ws[jj][tx<<2];
            acc[0][0] += a4.x*b4.x; acc[0][1] += a4.x*b4.y; acc[0][2] += a4.x*b4.z; acc[0][3] += a4.x*b4.w;
            acc[1][0] += a4.y*b4.x; acc[1][1] += a4.y*b4.y; acc[1][2] += a4.y*b4.z; acc[1][3] += a4.y*b4.w;
            acc[2][0] += a4.z*b4.x; acc[2][1] += a4.z*b4.y; acc[2][2] += a4.z*b4.z; acc[2][3] += a4.z*b4.w;
            acc[3][0] += a4.w*b4.x; acc[3][1] += a4.w*b4.y; acc[3][2] += a4.w*b4.z; acc[3][3] += a4.w*b4.w;
        }
    }
    int gk0 = bk + (ty << 2);
    int gn0 = bn + (tx << 2);
    #pragma unroll
    for (int ik = 0; ik < 4; ++ik) {
        int gk = gk0 + ik;
        if (gk >= 400) break;
        #pragma unroll
        for (int in = 0; in < 4; ++in) {
            int gn = gn0 + in;
            float v = (gn < 400) ? acc[ik][in] * scale : 0.f;
            unsigned short h16, l16; split2(v, h16, l16);
            dst[(size_t)gn*Kw + gk] = h16;
            dst[(size_t)512*Kw + (size_t)gn*Kw + gk] = l16;
        }
    }
}

// ---------------- prepvec: C_i, gv_i, scalar consts ----------------
__global__ __launch_bounds__(512) void prepvec_kernel(
    const float* __restrict__ scal,
    const float* __restrict__ csd, const float* __restrict__ css, const float* __restrict__ csb,
    const float* __restrict__ Wc, const float* __restrict__ bc,
    const float* __restrict__ clf_w, const float* __restrict__ Pb,
    float* __restrict__ cv, float* __restrict__ gv, float* __restrict__ scl2)
{
    int i = blockIdx.x;
    int t = threadIdx.x;
    const float* cw = clf_w + i*400;
    float ski = scal[i*8+4], cki = scal[i*8+5];
    if (t < 448) {
        float g = 0.f, c = 0.f;
        if (t < 400) {
            const float* wr = Wc + (size_t)i*5*160000 + (size_t)t*400;
            float s = 0.f;
            for (int j = 0; j < 400; ++j) s += wr[j]*cw[j];
            g = ski * s;
            if (i == 0) {
                c = scal[1]*csd[t] + scal[3]*css[t];
            } else {
                float s2 = scal[i*8+0], c2 = scal[i*8+1];
                float c1 = scal[i*8+3];
                float skp = scal[(i-1)*8+4], ckp = scal[(i-1)*8+5];
                const float* bcp = bc + (size_t)(i-1)*5*400;
                float bp = 0.f;
                for (int j = 0; j < 400; ++j) bp += bcp[j]*Pb[(size_t)j*400 + t];
                c = c1*css[t] + (c2 + s2*ckp)*csb[t] + s2*skp*bp;
            }
        }
        gv[i*448 + t] = g;
        cv[i*448 + t] = c;
    }
    // scalar: sum_j (ski*bc_i[j] + cki)*cw[j]
    __shared__ float red[8];
    float sc = 0.f;
    const float* bci = bc + (size_t)i*5*400;
    for (int j = t; j < 400; j += 512) sc += (ski*bci[j] + cki)*cw[j];
    for (int o = 32; o > 0; o >>= 1) sc += __shfl_down(sc, o);
    int wv = t >> 6, ln = t & 63;
    if (ln == 0) red[wv] = sc;
    __syncthreads();
    if (t == 0) scl2[i] = red[0]+red[1]+red[2]+red[3]+red[4]+red[5]+red[6]+red[7];
}

// ---------------- embed: node0/node1 bf16 hi/lo planes (padded strides) ----------------
__global__ __launch_bounds__(256) void embed_kernel(
    const float* __restrict__ rd, const int* __restrict__ rs,
    const float* __restrict__ emb,
    unsigned short* __restrict__ n0h, unsigned short* __restrict__ n0l,
    unsigned short* __restrict__ n1h, unsigned short* __restrict__ n1l,
    float* __restrict__ partial)
{
    int tid0 = blockIdx.x*256 + threadIdx.x;
    int nth = gridDim.x*256;
    float ssq = 0.f, dsq = 0.f;
    for (int it = tid0; it < 8192*26; it += nth) {
        int b = it / 26, s = it - b*26;
        int row = 13 + 50000*s + rs[b*26 + s];
        const float* e = emb + (size_t)row*16;
        float4 e0 = *(const float4*)&e[0], e1 = *(const float4*)&e[4];
        float4 e2 = *(const float4*)&e[8], e3 = *(const float4*)&e[12];
        float vv[16] = {e0.x,e0.y,e0.z,e0.w, e1.x,e1.y,e1.z,e1.w,
                        e2.x,e2.y,e2.z,e2.w, e3.x,e3.y,e3.z,e3.w};
        unsigned short hb[16], lb[16];
        for (int j = 0; j < 16; ++j) { ssq += vv[j]*vv[j]; split2(vv[j], hb[j], lb[j]); }
        size_t off = (size_t)b*SN1 + s*16;
        *(uint4*)&n1h[off] = *(uint4*)&hb[0]; *(uint4*)&n1h[off+8] = *(uint4*)&hb[8];
        *(uint4*)&n1l[off] = *(uint4*)&lb[0]; *(uint4*)&n1l[off+8] = *(uint4*)&lb[8];
    }
    for (int it = tid0; it < 8192*13; it += nth) {
        int b = it / 13, f = it - b*13;
        float sc = rd[b*13 + f];
        const float* e = emb + (size_t)f*16;
        float4 e0 = *(const float4*)&e[0], e1 = *(const float4*)&e[4];
        float4 e2 = *(const float4*)&e[8], e3 = *(const float4*)&e[12];
        float vv[16] = {e0.x,e0.y,e0.z,e0.w, e1.x,e1.y,e1.z,e1.w,
                        e2.x,e2.y,e2.z,e2.w, e3.x,e3.y,e3.z,e3.w};
        unsigned short hb[16], lb[16];
        for (int j = 0; j < 16; ++j) { float v = vv[j]*sc; dsq += v*v; split2(v, hb[j], lb[j]); }
        size_t off = (size_t)b*SN0 + f*16;
        *(uint4*)&n0h[off] = *(uint4*)&hb[0]; *(uint4*)&n0h[off+8] = *(uint4*)&hb[8];
        *(uint4*)&n0l[off] = *(uint4*)&lb[0]; *(uint4*)&n0l[off+8] = *(uint4*)&lb[8];
    }
    for (int o = 32; o > 0; o >>= 1) { ssq += __shfl_down(ssq, o); dsq += __shfl_down(dsq, o); }
    __shared__ float red[8];
    int wave = threadIdx.x >> 6, lane = threadIdx.x & 63;
    if (lane == 0) { red[wave] = dsq; red[4+wave] = ssq; }
    __syncthreads();
    if (threadIdx.x == 0) {
        partial[blockIdx.x*2]   = red[0]+red[1]+red[2]+red[3];
        partial[blockIdx.x*2+1] = red[4]+red[5]+red[6]+red[7];
    }
}

// blocks 0..31: out[b] = clf_b + sum_i scl2[i]; block 32: regs
__global__ __launch_bounds__(256) void finalize_kernel(
    const float* __restrict__ clf_b, const float* __restrict__ partial,
    const float* __restrict__ scl2, float* __restrict__ out)
{
    if (blockIdx.x < 32) {
        float base = clf_b[0] + scl2[0] + scl2[1] + scl2[2] + scl2[3];
        out[blockIdx.x*256 + threadIdx.x] = base;
        return;
    }
    float d = 0.f, s = 0.f;
    for (int i = threadIdx.x; i < EMB_BLOCKS; i += 256) { d += partial[2*i]; s += partial[2*i+1]; }
    for (int o = 32; o > 0; o >>= 1) { d += __shfl_down(d, o); s += __shfl_down(s, o); }
    __shared__ float red[8];
    int wave = threadIdx.x >> 6, lane = threadIdx.x & 63;
    if (lane == 0) { red[wave] = d; red[4+wave] = s; }
    __syncthreads();
    if (threadIdx.x == 0) {
        float dd = red[0]+red[1]+red[2]+red[3];
        float ss = red[4]+red[5]+red[6]+red[7];
        out[8192] = 1e-5f * (sqrtf(dd) + sqrtf(ss));
    }
}

// ---------------- LDS-staged split-bf16 MFMA GEMM (R7 structure) ----------------
// 256 blocks (64m x 4n tiles of 128, XCD swizzle), 512 thr = 8 waves (2m,2n,2k-split).
// Always relu. Fused logits via gv. ch==nullptr -> logits-only (no C store).
__global__ __launch_bounds__(512, 2) void mfma_gemm(
    const unsigned short* __restrict__ a1h, const unsigned short* __restrict__ a1l, int sA, int KA,
    const unsigned short* __restrict__ a2h, const unsigned short* __restrict__ a2l,
    const unsigned short* __restrict__ bph, int Kp, int Kw,
    const float* __restrict__ vec,
    unsigned short* __restrict__ ch, unsigned short* __restrict__ cl,
    const float* __restrict__ lw, float* __restrict__ lout)
{
    __shared__ __align__(16) unsigned short lds[2][2][2][128][24];
    const int BUFS = 2*128*24;
    const int PL   = 128*24;
    const int R32  = 32*24;

    int tid = threadIdx.x;
    int bid = blockIdx.x;
    int xcd = bid & 7, idx = bid >> 3;
    int mt = xcd*8 + (idx >> 2);
    int nt = idx & 3;
    int bm = mt * 128, bn = nt * 128;

    int W = tid >> 6, lane = tid & 63;
    int kw = W & 1, nw = (W >> 1) & 1, mw = W >> 2;
    int r31 = lane & 31, hh = lane >> 5;

    int sp  = tid >> 8;
    int srr = (tid >> 1) & 127;
    int sh8 = (tid & 1) * 8;

    const unsigned short* Arow1 = (sp ? a1l : a1h) + (size_t)(bm + srr)*sA + sh8;
    const unsigned short* Arow2 = (sp ? a2l : a2h) + (size_t)(bm + srr)*SN1 + sh8 - KA;
    const unsigned short* Brow  = bph + (size_t)sp*512*Kw + (size_t)(bn + srr)*Kw + sh8;

    unsigned short* wA = &lds[0][0][sp][srr][sh8];
    unsigned short* wB = &lds[1][0][sp][srr][sh8];
    const unsigned short* fA = &lds[0][0][0][mw*64 + r31][hh*8];
    const unsigned short* fB = &lds[1][0][0][nw*64 + r31][hh*8];

    int nk = Kp >> 4;

    floatx16 acc00, acc01, acc10, acc11;
    for (int i = 0; i < 16; ++i) { acc00[i]=0.f; acc01[i]=0.f; acc10[i]=0.f; acc11[i]=0.f; }

    #define GLOAD(K, AV, BV) do {                                              \
        int kb_ = (K) << 4;                                                    \
        AV = (kb_ < KA) ? *(const uint4*)(Arow1 + kb_)                         \
                        : *(const uint4*)(Arow2 + kb_);                        \
        BV = *(const uint4*)(Brow + kb_);                                      \
    } while(0)

    #define COMPUTE(BOFF) do {                                                 \
        const unsigned short* pa = fA + (BOFF);                                \
        const unsigned short* pb = fB + (BOFF);                                \
        short8 a0h = *(const short8*)(pa);                                     \
        short8 a1h_ = *(const short8*)(pa + R32);                              \
        short8 a0l = *(const short8*)(pa + PL);                                \
        short8 a1l_ = *(const short8*)(pa + PL + R32);                         \
        short8 b0h = *(const short8*)(pb);                                     \
        short8 b1h = *(const short8*)(pb + R32);                               \
        short8 b0l = *(const short8*)(pb + PL);                                \
        short8 b1l = *(const short8*)(pb + PL + R32);                          \
        acc00 = __builtin_amdgcn_mfma_f32_32x32x16_bf16(a0h, b0h, acc00,0,0,0);\
        acc01 = __builtin_amdgcn_mfma_f32_32x32x16_bf16(a0h, b1h, acc01,0,0,0);\
        acc10 = __builtin_amdgcn_mfma_f32_32x32x16_bf16(a1h_, b0h, acc10,0,0,0);\
        acc11 = __builtin_amdgcn_mfma_f32_32x32x16_bf16(a1h_, b1h, acc11,0,0,0);\
        acc00 = __builtin_amdgcn_mfma_f32_32x32x16_bf16(a0h, b0l, acc00,0,0,0);\
        acc01 = __builtin_amdgcn_mfma_f32_32x32x16_bf16(a0h, b1l, acc01,0,0,0);\
        acc10 = __builtin_amdgcn_mfma_f32_32x32x16_bf16(a1h_, b0l, acc10,0,0,0);\
        acc11 = __builtin_amdgcn_mfma_f32_32x32x16_bf16(a1h_, b1l, acc11,0,0,0);\
        acc00 = __builtin_amdgcn_mfma_f32_32x32x16_bf16(a0l, b0h, acc00,0,0,0);\
        acc01 = __builtin_amdgcn_mfma_f32_32x32x16_bf16(a0l, b1h, acc01,0,0,0);\
        acc10 = __builtin_amdgcn_mfma_f32_32x32x16_bf16(a1l_, b0h, acc10,0,0,0);\
        acc11 = __builtin_amdgcn_mfma_f32_32x32x16_bf16(a1l_, b1h, acc11,0,0,0);\
    } while(0)

    uint4 avA, bvA, avB, bvB;
    GLOAD(0, avA, bvA);
    if (nk > 1) GLOAD(1, avB, bvB);

    int k = 0;
    while (true) {
        *(uint4*)(wA) = avA;
        *(uint4*)(wB) = bvA;
        __syncthreads();
        if (k + 2 < nk) GLOAD(k + 2, avA, bvA);
        if (kw == 0) COMPUTE(0);
        if (++k >= nk) break;
        *(uint4*)(wA + BUFS) = avB;
        *(uint4*)(wB + BUFS) = bvB;
        __syncthreads();
        if (k + 2 < nk) GLOAD(k + 2, avB, bvB);
        if (kw == 1) COMPUTE(BUFS);
        if (++k >= nk) break;
    }
    #undef GLOAD
    #undef COMPUTE

    __syncthreads();

    float* red = (float*)&lds[0][0][0][0][0];
    int wp = W >> 1;
    float* myred = red + (wp*64 + lane)*36;

    #pragma unroll
    for (int r = 0; r < 2; ++r) {
        const floatx16& aq0 = r ? acc10 : acc00;
        const floatx16& aq1 = r ? acc11 : acc01;
        if (kw == 1) {
            #pragma unroll
            for (int j4 = 0; j4 < 4; ++j4) {
                *(float4*)(myred + j4*4)      = make_float4(aq0[j4*4+0],aq0[j4*4+1],aq0[j4*4+2],aq0[j4*4+3]);
                *(float4*)(myred + 16 + j4*4) = make_float4(aq1[j4*4+0],aq1[j4*4+1],aq1[j4*4+2],aq1[j4*4+3]);
            }
        }
        __syncthreads();
        if (kw == 0) {
            int gn0 = bn + nw*64 + r31;
            int gn1 = gn0 + 32;
            bool ok0 = gn0 < 400, ok1 = gn1 < 400;
            float vc0 = ok0 ? vec[gn0] : 0.f;
            float vc1 = ok1 ? vec[gn1] : 0.f;
            float wv0 = ok0 ? lw[gn0] : 0.f;
            float wv1 = ok1 ? lw[gn1] : 0.f;
            #pragma unroll
            for (int j = 0; j < 16; ++j) {
                int gm = bm + mw*64 + r*32 + (j & 3) + 8*(j >> 2) + 4*hh;
                float v0 = aq0[j] + myred[j] + vc0;
                float v1 = aq1[j] + myred[16 + j] + vc1;
                v0 = fmaxf(v0, 0.f); v1 = fmaxf(v1, 0.f);
                if (ch) {
                    if (ok0) {
                        unsigned short h16, l16; split2(v0, h16, l16);
                        ch[(size_t)gm*SH + gn0] = h16;
                        cl[(size_t)gm*SH + gn0] = l16;
                    }
                    if (ok1) {
                        unsigned short h16, l16; split2(v1, h16, l16);
                        ch[(size_t)gm*SH + gn1] = h16;
                        cl[(size_t)gm*SH + gn1] = l16;
                    }
                }
                float lv = v0*wv0 + v1*wv1;
                #pragma unroll
                for (int o = 1; o < 32; o <<= 1) lv += __shfl_xor(lv, o);
                if (r31 == 0) atomicAdd(&lout[gm], lv);
            }
        }
        __syncthreads();
    }
}

// ---------------- host ----------------
static inline size_t align64(size_t x) { return (x + 63) & ~(size_t)63; }

extern "C" void kernel_launch(void* const* d_in, const int* in_sizes, int n_in,
                              void* d_out, int out_size, void* d_ws, size_t ws_size,
                              hipStream_t stream)
{
    const float* raw_dense  = (const float*)d_in[0];
    const int*   raw_sparse = (const int*)d_in[1];
    const float* emb   = (const float*)d_in[2];
    const float* Pd    = (const float*)d_in[3];
    const float* Ps    = (const float*)d_in[4];
    const float* Pb    = (const float*)d_in[5];
    const float* Wc    = (const float*)d_in[6];
    const float* bc    = (const float*)d_in[7];
    const float* clf_w = (const float*)d_in[8];
    const float* clf_b = (const float*)d_in[9];
    const float* a0 = (const float*)d_in[10];
    const float* a1 = (const float*)d_in[11];
    const float* a2 = (const float*)d_in[12];
    const float* a3 = (const float*)d_in[13];
    float* out = (float*)d_out;

    char* p = (char*)d_ws;
    auto alloc = [&](size_t bytes) { char* r = p; p += align64(bytes); return r; };

    float* scal    = (float*)alloc(32*4);
    float* partial = (float*)alloc(2*EMB_BLOCKS*4);
    float* csd     = (float*)alloc(400*4);
    float* css     = (float*)alloc(400*4);
    float* csb     = (float*)alloc(400*4);
    float* cv      = (float*)alloc(4*448*4);
    float* gv      = (float*)alloc(4*448*4);
    float* scl2    = (float*)alloc(16*4);
    unsigned short* w0 = (unsigned short*)alloc((size_t)2*512*640*2);
    unsigned short* w1 = (unsigned short*)alloc((size_t)2*512*832*2);
    unsigned short* w2 = (unsigned short*)alloc((size_t)2*512*832*2);
    unsigned short* w3 = (unsigned short*)alloc((size_t)2*512*832*2);
    unsigned short* n0h = (unsigned short*)alloc((size_t)8192*SN0*2);
    unsigned short* n0l = (unsigned short*)alloc((size_t)8192*SN0*2);
    unsigned short* n1h = (unsigned short*)alloc((size_t)8192*SN1*2);
    unsigned short* n1l = (unsigned short*)alloc((size_t)8192*SN1*2);
    unsigned short* hAh = (unsigned short*)alloc((size_t)8192*SH*2);
    unsigned short* hAl = (unsigned short*)alloc((size_t)8192*SH*2);
    unsigned short* hBh = (unsigned short*)alloc((size_t)8192*SH*2);
    unsigned short* hBl = (unsigned short*)alloc((size_t)8192*SH*2);

    prep1_kernel<<<5,256,0,stream>>>(Pd,Ps,Pb,a0,a1,a2,a3,scal,csd,css,csb);
    embed_kernel<<<EMB_BLOCKS,256,0,stream>>>(raw_dense, raw_sparse, emb, n0h,n0l,n1h,n1l, partial);
    prepM_kernel<<<dim3(8,7,3),256,0,stream>>>(Wc,Pb,scal,w1,w2,w3);
    prep2_kernel<<<dim3(8,13,4),256,0,stream>>>(Pd,Ps,Pb,scal,w0,w1,w2,w3);
    prepvec_kernel<<<4,512,0,stream>>>(scal,csd,css,csb,Wc,bc,clf_w,Pb,cv,gv,scl2);
    finalize_kernel<<<33,256,0,stream>>>(clf_b, partial, scl2, out);

    // h0 = relu([node0|node1]@w0 + cv0); logits += h0@gv0
    mfma_gemm<<<256,512,0,stream>>>(n0h,n0l,SN0,208, n1h,n1l, w0, 624,640, cv+0,    hAh,hAl, gv+0,    out);
    // h1 = relu([h0|node1]@w1 + cv1); logits += h1@gv1
    mfma_gemm<<<256,512,0,stream>>>(hAh,hAl,SH,400,  n1h,n1l, w1, 816,832, cv+448,  hBh,hBl, gv+448,  out);
    // h2
    mfma_gemm<<<256,512,0,stream>>>(hBh,hBl,SH,400,  n1h,n1l, w2, 816,832, cv+896,  hAh,hAl, gv+896,  out);
    // h3: logits only, no store
    mfma_gemm<<<256,512,0,stream>>>(hAh,hAl,SH,400,  n1h,n1l, w3, 816,832, cv+1344, nullptr,nullptr, gv+1344, out);
}